// Round 1
// baseline (690.988 us; speedup 1.0000x reference)
//
#include <hip/hip_runtime.h>

// out[b, l] = x[b, idx[l]]
// B=16384, I=4096 (row = 16 KiB), L=8192. fp32 in/out, int32 indices.
//
// v2 strategy: 8 rows per block, 512 threads.
//  - idx (32 KiB, identical for all rows) loaded ONCE per block into VGPRs
//    (4 x int4 per thread), reused for all 8 rows.
//  - x rows staged via async global_load_lds (width 16) into a
//    double-buffered LDS pair: stage row r+1 while gathering row r, so HBM
//    latency hides under the gather/store phase instead of a bare barrier.
//  - Full unroll => buffer index is compile-time (no scratch, ds_read with
//    immediate-folded base).
// Occupancy: 32 KiB LDS + 512 thr -> 4 blocks/CU = 32 waves/CU (full).
// Memory floor: 256 MiB read + 512 MiB write ~ 122 us at 6.3 TB/s.

#define NUM_INPUTS 4096
#define NUM_LEAVES 8192
#define ROWS 8
#define T 512

__device__ __forceinline__ void stage16(const float4* g, float* lds_uniform) {
    // gptr is per-lane; LDS dest is wave-uniform base + lane*16 (HW rule).
    __builtin_amdgcn_global_load_lds(
        (const __attribute__((address_space(1))) void*)(const void*)g,
        (__attribute__((address_space(3))) void*)(void*)lds_uniform,
        16, 0, 0);
}

__global__ __launch_bounds__(T) void frozenInputToLeaf_gather2(
    const float* __restrict__ x,
    const int* __restrict__ idx,
    float* __restrict__ out) {
    __shared__ float rows[2][NUM_INPUTS];

    const int t = threadIdx.x;
    const int wave = t >> 6;   // 0..7, wave-uniform
    const int lane = t & 63;
    const size_t b0 = (size_t)blockIdx.x * ROWS;

    // Load idx once per block: 8192 int32 = 2048 int4, 512 threads -> 4 each.
    int4 id[4];
    const int4* __restrict__ idx4 = (const int4*)idx;
#pragma unroll
    for (int v = 0; v < 4; ++v) id[v] = idx4[v * T + t];

    // Prologue: stage row b0 into buffer 0.
    // Row = 1024 float4 = 16 chunks of (64 lanes x 16 B). Wave w takes
    // chunks w and w+8; each instruction fills 1 KiB of LDS linearly.
    {
        const float4* __restrict__ g = (const float4*)(x + b0 * NUM_INPUTS);
#pragma unroll
        for (int j = 0; j < 2; ++j) {
            const int c = j * 8 + wave;
            stage16(g + c * 64 + lane, &rows[0][c * 256]);
        }
    }
    __syncthreads();  // drains vmcnt(0): row b0 resident

#pragma unroll
    for (int r = 0; r < ROWS; ++r) {
        const int cur = r & 1;  // compile-time after full unroll

        // Prefetch row r+1 into the other buffer (async, no wait here).
        if (r + 1 < ROWS) {
            const float4* __restrict__ g =
                (const float4*)(x + (b0 + r + 1) * NUM_INPUTS);
#pragma unroll
            for (int j = 0; j < 2; ++j) {
                const int c = j * 8 + wave;
                stage16(g + c * 64 + lane, &rows[cur ^ 1][c * 256]);
            }
        }

        // Gather + coalesced store of row r: 2048 float4, 512 thr -> 4 each.
        float4* __restrict__ o4 = (float4*)(out + (b0 + r) * NUM_LEAVES);
#pragma unroll
        for (int v = 0; v < 4; ++v) {
            float4 o;
            o.x = rows[cur][id[v].x];
            o.y = rows[cur][id[v].y];
            o.z = rows[cur][id[v].z];
            o.w = rows[cur][id[v].w];
            o4[v * T + t] = o;
        }

        // One barrier per row: waits gather readers of rows[cur] (WAR safety
        // for the stage in iteration r+1) AND vmcnt(0) for the prefetch, so
        // rows[cur^1] is resident when iteration r+1 reads it.
        __syncthreads();
    }
}

extern "C" void kernel_launch(void* const* d_in, const int* in_sizes, int n_in,
                              void* d_out, int out_size, void* d_ws, size_t ws_size,
                              hipStream_t stream) {
    const float* x = (const float*)d_in[0];
    const int* idx = (const int*)d_in[1];
    float* out = (float*)d_out;

    const int batch = in_sizes[0] / NUM_INPUTS;  // 16384
    frozenInputToLeaf_gather2<<<batch / ROWS, T, 0, stream>>>(x, idx, out);
}